// Round 2
// baseline (201.772 us; speedup 1.0000x reference)
//
#include <hip/hip_runtime.h>

// out[r] = sum_{s in ray r} w[s] * rgb[s,:]  (segment_ids sorted, fp32)
// Wave-autonomous, barrier-free, LDS-free.
// v3: persistent waves + software-pipelined streaming.
//   - grid sized to exactly fill the chip (4 blocks/CU, 16 waves/CU)
//   - each wave owns a contiguous 2048-sample span = 8 chunks x 256 samples
//   - ping-pong double buffer: loads for chunk c+1 issued before chunk c is
//     merged -> continuous per-wave load issue (copy-ubench pattern) instead
//     of one burst + long vmcnt drain
//   - per chunk: per-lane run merge + 6-step segmented shuffle scan + one
//     atomicAdd triplet per run-end (out pre-zeroed); chunk boundaries flush
//     like wave boundaries (correct by atomic accumulation)

#define NTHREADS 256
#define WAVES_PER_BLOCK (NTHREADS / 64)
#define CPL 4                 // samples per lane per chunk
#define CHUNK (64 * CPL)      // 256 samples per wave-chunk
#define CHUNKS 8              // chunks per wave (even)
#define SPW (CHUNK * CHUNKS)  // 2048 samples per wave

__global__ __launch_bounds__(NTHREADS) void zero_out_kernel(float4* __restrict__ out4,
                                                            int n4) {
  int i = blockIdx.x * blockDim.x + threadIdx.x;
  if (i < n4) out4[i] = make_float4(0.f, 0.f, 0.f, 0.f);
}

__device__ __forceinline__ void process_chunk(const int4 id4, const float4 w4,
                                              const float4 r0, const float4 r1,
                                              const float4 r2, const int lane,
                                              float* __restrict__ out) {
  int idv[CPL] = {id4.x, id4.y, id4.z, id4.w};
  float px[CPL], py[CPL], pz[CPL];
  px[0] = r0.x * w4.x; py[0] = r0.y * w4.x; pz[0] = r0.z * w4.x;
  px[1] = r0.w * w4.y; py[1] = r1.x * w4.y; pz[1] = r1.y * w4.y;
  px[2] = r1.z * w4.z; py[2] = r1.w * w4.z; pz[2] = r2.x * w4.z;
  px[3] = r2.y * w4.w; py[3] = r2.z * w4.w; pz[3] = r2.w * w4.w;

  // ---- per-lane sequential run merge (ids sorted within lane) ------------
  const int first_id = idv[0];
  int run_id = first_id;
  float rx = px[0], ry = py[0], rz = pz[0];
  float hx = 0.f, hy = 0.f, hz = 0.f;
  bool f_intra = false;  // true once a run boundary occurred inside this lane
  #pragma unroll
  for (int k = 1; k < CPL; ++k) {
    if (idv[k] == run_id) {
      rx += px[k]; ry += py[k]; rz += pz[k];
    } else {
      if (!f_intra) {
        hx = rx; hy = ry; hz = rz; f_intra = true;  // stash head run
      } else {  // interior complete run (rare) -> direct flush
        atomicAdd(&out[3 * run_id + 0], rx);
        atomicAdd(&out[3 * run_id + 1], ry);
        atomicAdd(&out[3 * run_id + 2], rz);
      }
      run_id = idv[k];
      rx = px[k]; ry = py[k]; rz = pz[k];
    }
  }
  const int last_id = run_id;

  // ---- cross-lane segmented scan over tail partials ----------------------
  const int prev_tid = __shfl_up(last_id, 1, 64);  // tail id of lane-1
  int fl = (lane == 0 || f_intra || prev_tid != first_id) ? 1 : 0;
  float sx = rx, sy = ry, sz = rz;
  #pragma unroll
  for (int off = 1; off < 64; off <<= 1) {
    const float ox = __shfl_up(sx, off, 64);
    const float oy = __shfl_up(sy, off, 64);
    const float oz = __shfl_up(sz, off, 64);
    const int ofl = __shfl_up(fl, off, 64);
    if (lane >= off && fl == 0) { sx += ox; sy += oy; sz += oz; fl = ofl; }
  }

  // head-run flush: run ending inside this lane at the head prefix
  const float pSx = __shfl_up(sx, 1, 64);
  const float pSy = __shfl_up(sy, 1, 64);
  const float pSz = __shfl_up(sz, 1, 64);
  if (f_intra) {
    const bool link = (lane > 0) && (prev_tid == first_id);
    atomicAdd(&out[3 * first_id + 0], hx + (link ? pSx : 0.f));
    atomicAdd(&out[3 * first_id + 1], hy + (link ? pSy : 0.f));
    atomicAdd(&out[3 * first_id + 2], hz + (link ? pSz : 0.f));
  }

  // tail-run flush: last lane of each run within the wave-chunk
  const int next_hid = __shfl_down(first_id, 1, 64);  // head id of lane+1
  if (lane == 63 || next_hid != last_id) {
    atomicAdd(&out[3 * last_id + 0], sx);
    atomicAdd(&out[3 * last_id + 1], sy);
    atomicAdd(&out[3 * last_id + 2], sz);
  }
}

__global__ __launch_bounds__(NTHREADS, 4) void integrate_kernel(
    const int* __restrict__ ids, const float* __restrict__ rgb,
    const float* __restrict__ w, float* __restrict__ out, int n_samples) {
  const int lane = threadIdx.x & 63;
  const long long wave_id =
      (long long)blockIdx.x * WAVES_PER_BLOCK + (threadIdx.x >> 6);
  const long long span0 = wave_id * SPW;
  if (span0 >= (long long)n_samples) return;

  if (span0 + SPW <= (long long)n_samples) {
    // ---- fast path: fully in-range, 16B-aligned; ping-pong pipeline ------
    const long long lb = span0 + (long long)lane * CPL;
    int4 Ai; float4 Aw, Ar0, Ar1, Ar2;
    int4 Bi; float4 Bw, Br0, Br1, Br2;
#define LOADX(P, c)                                   \
    do {                                              \
      const long long b_ = lb + (long long)(c) * CHUNK; \
      P##i  = *(const int4*)(ids + b_);               \
      P##w  = *(const float4*)(w + b_);               \
      P##r0 = *(const float4*)(rgb + 3 * b_);         \
      P##r1 = *(const float4*)(rgb + 3 * b_ + 4);     \
      P##r2 = *(const float4*)(rgb + 3 * b_ + 8);     \
    } while (0)
    LOADX(A, 0);
    #pragma unroll
    for (int c = 0; c < CHUNKS; c += 2) {
      LOADX(B, c + 1);  // prefetch next chunk before consuming current
      process_chunk(Ai, Aw, Ar0, Ar1, Ar2, lane, out);
      if (c + 2 < CHUNKS) LOADX(A, c + 2);
      process_chunk(Bi, Bw, Br0, Br1, Br2, lane, out);
    }
#undef LOADX
  } else {
    // ---- tail path: bounds-checked scalar gather per chunk ---------------
    // Pads replicate the previous id with zero weight -> zero contribution,
    // keeping all 64 lanes shuffle-active.
    const int last = ids[n_samples - 1];
    for (int c = 0; c < CHUNKS; ++c) {
      const long long cb = span0 + (long long)c * CHUNK;
      if (cb >= (long long)n_samples) break;  // wave-uniform
      int idt[CPL]; float wt[CPL], rt[3 * CPL];
      #pragma unroll
      for (int j = 0; j < CPL; ++j) {
        const long long s = cb + (long long)lane * CPL + j;
        if (s < (long long)n_samples) {
          idt[j] = ids[s];
          wt[j] = w[s];
          rt[3 * j + 0] = rgb[3 * s + 0];
          rt[3 * j + 1] = rgb[3 * s + 1];
          rt[3 * j + 2] = rgb[3 * s + 2];
        } else {
          idt[j] = (j == 0) ? last : idt[j - 1];
          wt[j] = 0.f;
          rt[3 * j + 0] = rt[3 * j + 1] = rt[3 * j + 2] = 0.f;
        }
      }
      const int4 i4 = make_int4(idt[0], idt[1], idt[2], idt[3]);
      const float4 w4 = make_float4(wt[0], wt[1], wt[2], wt[3]);
      const float4 r0 = make_float4(rt[0], rt[1], rt[2], rt[3]);
      const float4 r1 = make_float4(rt[4], rt[5], rt[6], rt[7]);
      const float4 r2 = make_float4(rt[8], rt[9], rt[10], rt[11]);
      process_chunk(i4, w4, r0, r1, r2, lane, out);
    }
  }
}

extern "C" void kernel_launch(void* const* d_in, const int* in_sizes, int n_in,
                              void* d_out, int out_size, void* d_ws, size_t ws_size,
                              hipStream_t stream) {
  const int*   segment_ids = (const int*)d_in[0];
  const float* rgb         = (const float*)d_in[1];
  const float* weights     = (const float*)d_in[2];
  float*       out         = (float*)d_out;

  const int n_samples = in_sizes[0];

  {  // zero output (all contributions arrive via atomics)
    int n4 = out_size / 4;  // out_size = n_rays*3*4B, divisible by 16
    int blocks = (n4 + NTHREADS - 1) / NTHREADS;
    zero_out_kernel<<<blocks, NTHREADS, 0, stream>>>((float4*)out, n4);
  }
  {
    long long waves = ((long long)n_samples + SPW - 1) / SPW;
    int blocks = (int)((waves + WAVES_PER_BLOCK - 1) / WAVES_PER_BLOCK);
    integrate_kernel<<<blocks, NTHREADS, 0, stream>>>(
        segment_ids, rgb, weights, out, n_samples);
  }
}